// Round 13
// baseline (1244.759 us; speedup 1.0000x reference)
//
#include <hip/hip_runtime.h>
#include <stdint.h>

#define HID    2048
#define MPTS   16425
#define MTILES 129    // ceil(16425/128)
#define NTIL   16     // 2048/128
#define KTIL   64     // 2048/32
#define BIMG   5120   // f16 elems per packed padded B tile image (128 rows * 40)

typedef float    f32x4 __attribute__((ext_vector_type(4)));
typedef _Float16 f16x8 __attribute__((ext_vector_type(8)));

// P-layout (A-operand fragment order) for activations:
// elem(row, k) -> linear ((tile*64+kt)<<12) + rowgrp*512 + quad*128 + lidx*8 + j
// Consumer wave A-frag load = base + lane*8 halves (1KB fully coalesced).

// ---------------------------------------------------------------------------
// Pack fp32 W (K x N row-major) into single-fp16 padded tile images:
// img(L,nt,kt)[n*40+k] = (f16)W[kt*32+k][nt*128+n]; pad k=32..39 zeros.
// ---------------------------------------------------------------------------
__global__ void pack_w16(const float* __restrict__ w1,
                         const float* __restrict__ w2,
                         const float* __restrict__ w3,
                         _Float16* __restrict__ wp) {
    const int kt = blockIdx.x, nt = blockIdx.y, L = blockIdx.z;
    const float* W = (L == 0) ? w1 : ((L == 1) ? w2 : w3);
    __shared__ float tl[128 * 33];   // [n][k] transposed, padded
    const int tid = threadIdx.x;
    const int k  = tid >> 3;          // 0..31
    const int nc = (tid & 7) * 16;    // 0..112
    const float* src = W + (size_t)(kt * 32 + k) * HID + nt * 128 + nc;
    #pragma unroll
    for (int j = 0; j < 16; ++j) tl[(nc + j) * 33 + k] = src[j];
    __syncthreads();
    const size_t base = (size_t)(L * 1024 + nt * 64 + kt) * BIMG;
    for (int e = tid; e < BIMG; e += 256) {
        int n = e / 40, kk = e - n * 40;
        wp[base + e] = (kk < 32) ? (_Float16)tl[n * 33 + kk] : (_Float16)0.f;
    }
}

// ---------------------------------------------------------------------------
// Layer 0: v=relu(xs*w0+b0); store fp16 hi/lo pair in P-layout
// ---------------------------------------------------------------------------
__global__ void layer0p(const float* __restrict__ xs,
                        const float* __restrict__ w0,
                        const float* __restrict__ b0,
                        _Float16* __restrict__ Ahg,
                        _Float16* __restrict__ Alg, int row0) {
    const int r = blockIdx.x;             // chunk-local row
    const int grow = row0 + r;
    const int j0 = threadIdx.x * 8;       // k
    const float x = (grow < MPTS) ? xs[grow] : 0.f;
    f16x8 h, l;
    #pragma unroll
    for (int q = 0; q < 8; ++q) {
        float v = x * w0[j0 + q] + b0[j0 + q];
        v = v > 0.f ? v : 0.f;
        _Float16 hs = (_Float16)v;
        h[q] = hs;
        l[q] = (_Float16)(v - (float)hs);
    }
    const int t = r >> 7, rowgrp = (r >> 4) & 7, lidx = r & 15;
    const int kt = j0 >> 5, quad = (j0 >> 3) & 3;
    const size_t dst = ((size_t)(t * 64 + kt) << 12) + rowgrp * 512 + quad * 128 + lidx * 8;
    *(f16x8*)(Ahg + dst) = h;
    *(f16x8*)(Alg + dst) = l;
}

// ---------------------------------------------------------------------------
// MFMA GEMM v6 (fp16, wide-N): block = 128M x 256N (two B images per kt),
// 4 waves of 64x128. A (P-layout hi/lo) direct from global, coalesced;
// W via global_load_lds, double-buffered. One barrier per kt, 2x MFMA per
// barrier vs v5 -> drain amortized. Grid (mt, nt2); mt-count % 8 == 0 puts
// all nt2-blocks of one mt on the same XCD (A-tile L2-local).
// ---------------------------------------------------------------------------
__launch_bounds__(256, 2)
__global__ void gemm_hl(const _Float16* __restrict__ Ahg,
                        const _Float16* __restrict__ Alg,
                        const _Float16* __restrict__ wp,
                        const float* __restrict__ bias,
                        _Float16* __restrict__ Chg,
                        _Float16* __restrict__ Clg,
                        int layer, int write_lo) {
    __shared__ _Float16 Bs[2][2][BIMG];   // [dbuf][image][...]

    const int tid  = threadIdx.x;
    const int lane = tid & 63;
    const int wave = tid >> 6;
    const int quad = lane >> 4;
    const int lidx = lane & 15;
    const int mt  = blockIdx.x;          // chunk-local M tile
    const int nt2 = blockIdx.y;          // 0..7 -> cols [nt2*256, nt2*256+256)
    const int mbase = (wave >> 1) * 64;
    const int wimg  = wave & 1;          // which of the 2 B images this wave uses

    const char* gW0 = (const char*)(wp + (size_t)(layer * 1024 + (nt2 * 2 + 0) * 64) * BIMG);
    const char* gW1 = (const char*)(wp + (size_t)(layer * 1024 + (nt2 * 2 + 1) * 64) * BIMG);

    const size_t abase = ((size_t)(mt * 64) << 12) + (size_t)(mbase >> 4) * 512 + (size_t)lane * 8;
    const _Float16* aH = Ahg + abase;
    const _Float16* aL = Alg + abase;

    f32x4 acc[4][8];
    #pragma unroll
    for (int i = 0; i < 4; ++i)
        #pragma unroll
        for (int j = 0; j < 8; ++j) acc[i][j] = (f32x4)0.f;

    // prologue: stage kt=0 (both images) into buffer 0
    for (int t = wave; t < 10; t += 4) {
        __builtin_amdgcn_global_load_lds(
            (const __attribute__((address_space(1))) unsigned int*)(gW0 + t * 1024 + lane * 16),
            (__attribute__((address_space(3))) unsigned int*)((char*)&Bs[0][0][0] + t * 1024),
            16, 0, 0);
        __builtin_amdgcn_global_load_lds(
            (const __attribute__((address_space(1))) unsigned int*)(gW1 + t * 1024 + lane * 16),
            (__attribute__((address_space(3))) unsigned int*)((char*)&Bs[0][1][0] + t * 1024),
            16, 0, 0);
    }
    __syncthreads();

    for (int kt = 0; kt < KTIL; ++kt) {
        const int buf = kt & 1;

        // prefetch next kt (both images) into the other buffer
        if (kt + 1 < KTIL) {
            const size_t off = (size_t)(kt + 1) * (BIMG * 2);
            char* d0 = (char*)&Bs[buf ^ 1][0][0];
            char* d1 = (char*)&Bs[buf ^ 1][1][0];
            for (int t = wave; t < 10; t += 4) {
                __builtin_amdgcn_global_load_lds(
                    (const __attribute__((address_space(1))) unsigned int*)(gW0 + off + t * 1024 + lane * 16),
                    (__attribute__((address_space(3))) unsigned int*)(d0 + t * 1024),
                    16, 0, 0);
                __builtin_amdgcn_global_load_lds(
                    (const __attribute__((address_space(1))) unsigned int*)(gW1 + off + t * 1024 + lane * 16),
                    (__attribute__((address_space(3))) unsigned int*)(d1 + t * 1024),
                    16, 0, 0);
            }
        }

        // A fragments: coalesced 1KB loads from P-layout global
        const size_t ak = (size_t)kt << 12;
        f16x8 afh[4], afl[4];
        #pragma unroll
        for (int mm = 0; mm < 4; ++mm) {
            afh[mm] = *(const f16x8*)(aH + ak + mm * 512);
            afl[mm] = *(const f16x8*)(aL + ak + mm * 512);
        }

        // B fragments from LDS: this wave's image, 8 col-groups of 16
        f16x8 bfr[8];
        #pragma unroll
        for (int nn = 0; nn < 8; ++nn) {
            int r = nn * 16 + lidx;
            bfr[nn] = *(const f16x8*)(&Bs[buf][wimg][r * 40 + quad * 8]);
        }

        #pragma unroll
        for (int mm = 0; mm < 4; ++mm)
            #pragma unroll
            for (int nn = 0; nn < 8; ++nn) {
                acc[mm][nn] = __builtin_amdgcn_mfma_f32_16x16x32_f16(afh[mm], bfr[nn], acc[mm][nn], 0, 0, 0);
                acc[mm][nn] = __builtin_amdgcn_mfma_f32_16x16x32_f16(afl[mm], bfr[nn], acc[mm][nn], 0, 0, 0);
            }

        __syncthreads();   // reads of buf done; prefetch into buf^1 drained
    }

    // epilogue: C/D layout col=lane&15, row=quad*4+reg; write P-layout pair
    #pragma unroll
    for (int nn = 0; nn < 8; ++nn) {
        const int col = nt2 * 256 + wimg * 128 + nn * 16 + lidx;   // k of next layer
        const float bv = bias[col];
        const int kt2 = col >> 5, quad2 = (col >> 3) & 3, j2 = col & 7;
        const size_t cb = ((size_t)(mt * 64 + kt2) << 12) + quad2 * 128 + j2;
        #pragma unroll
        for (int mm = 0; mm < 4; ++mm) {
            const int rowg = (mbase >> 4) + mm;             // rowgrp
            #pragma unroll
            for (int r = 0; r < 4; ++r) {
                const int lidx2 = quad * 4 + r;             // row & 15
                float v = acc[mm][nn][r] + bv;
                v = v > 0.f ? v : 0.f;
                _Float16 hs = (_Float16)v;
                const size_t idx = cb + rowg * 512 + lidx2 * 8;
                Chg[idx] = hs;
                if (write_lo) Clg[idx] = (_Float16)(v - (float)hs);
            }
        }
    }
}

// ---------------------------------------------------------------------------
// Layer 4 (P-layout hi only): one block per tile; t: row=t&127, half=t>>7
// ---------------------------------------------------------------------------
__global__ void layer4p(const _Float16* __restrict__ Ahg,
                        const float* __restrict__ w4,
                        const float* __restrict__ b4,
                        float* __restrict__ Amg, int row0) {
    __shared__ float ps[256];
    const int mt = blockIdx.x;
    const int t = threadIdx.x;
    const int row = t & 127, half = t >> 7;
    const int rowgrp = row >> 4, lidx = row & 15;
    const size_t base = ((size_t)(mt * 64) << 12) + rowgrp * 512 + lidx * 8;
    float s = 0.f;
    for (int kt = half * 32; kt < half * 32 + 32; ++kt) {
        const _Float16* ph = Ahg + base + ((size_t)kt << 12);
        const float* wv = w4 + kt * 32;
        #pragma unroll
        for (int quad = 0; quad < 4; ++quad) {
            f16x8 hv = *(const f16x8*)(ph + quad * 128);
            #pragma unroll
            for (int j = 0; j < 8; ++j)
                s += (float)hv[j] * wv[quad * 8 + j];
        }
    }
    ps[t] = s;
    __syncthreads();
    if (t < 128) {
        const int grow = row0 + mt * 128 + t;
        if (grow < MPTS) {
            float v = ps[t] + ps[t + 128] + b4[0];
            Amg[grow] = v > 0.f ? v : 0.f;
        }
    }
}

// ---------------------------------------------------------------------------
// Fallback fp32 path (ws too small for packed images)
// ---------------------------------------------------------------------------
__global__ void layer0f(const float* __restrict__ xs, const float* __restrict__ w0,
                        const float* __restrict__ b0, float* __restrict__ A, int row0) {
    const int r = blockIdx.x;
    const int j = threadIdx.x * 8;
    const float x = (row0 + r < MPTS) ? xs[row0 + r] : 0.f;
    float* out = A + (size_t)r * HID + j;
    #pragma unroll
    for (int q = 0; q < 8; ++q) {
        float v = x * w0[j + q] + b0[j + q];
        out[q] = v > 0.f ? v : 0.f;
    }
}

__launch_bounds__(256)
__global__ void gemm_valu(const float* __restrict__ A, const float* __restrict__ W,
                          const float* __restrict__ bias, float* __restrict__ C) {
    __shared__ float As[16][132];
    __shared__ float Ws[16][132];
    const int tid = threadIdx.x;
    const int tx = tid & 15, ty = tid >> 4;
    const int n0 = blockIdx.x * 128;
    const int m0 = blockIdx.y * 128;
    const int am = tid & 127, ak = (tid >> 7) * 8;
    const int wn = (tid & 15) * 8, wk = tid >> 4;
    const float* aptr = A + (size_t)(m0 + am) * HID + ak;
    const float* wptr = W + (size_t)wk * HID + n0 + wn;
    float acc[8][8];
    #pragma unroll
    for (int i = 0; i < 8; ++i)
        #pragma unroll
        for (int j = 0; j < 8; ++j) acc[i][j] = 0.f;
    for (int k0 = 0; k0 < HID; k0 += 16) {
        f32x4 a0 = *(const f32x4*)(aptr + k0);
        f32x4 a1 = *(const f32x4*)(aptr + k0 + 4);
        f32x4 w0v = *(const f32x4*)(wptr + (size_t)k0 * HID);
        f32x4 w1v = *(const f32x4*)(wptr + (size_t)k0 * HID + 4);
        __syncthreads();
        As[ak + 0][am] = a0[0]; As[ak + 1][am] = a0[1];
        As[ak + 2][am] = a0[2]; As[ak + 3][am] = a0[3];
        As[ak + 4][am] = a1[0]; As[ak + 5][am] = a1[1];
        As[ak + 6][am] = a1[2]; As[ak + 7][am] = a1[3];
        *(f32x4*)&Ws[wk][wn]     = w0v;
        *(f32x4*)&Ws[wk][wn + 4] = w1v;
        __syncthreads();
        #pragma unroll
        for (int kk = 0; kk < 16; ++kk) {
            f32x4 av0 = *(const f32x4*)&As[kk][ty * 8];
            f32x4 av1 = *(const f32x4*)&As[kk][ty * 8 + 4];
            f32x4 bv0 = *(const f32x4*)&Ws[kk][tx * 8];
            f32x4 bv1 = *(const f32x4*)&Ws[kk][tx * 8 + 4];
            float a[8] = {av0[0], av0[1], av0[2], av0[3], av1[0], av1[1], av1[2], av1[3]};
            float b[8] = {bv0[0], bv0[1], bv0[2], bv0[3], bv1[0], bv1[1], bv1[2], bv1[3]};
            #pragma unroll
            for (int i = 0; i < 8; ++i)
                #pragma unroll
                for (int j = 0; j < 8; ++j) acc[i][j] += a[i] * b[j];
        }
    }
    #pragma unroll
    for (int i = 0; i < 8; ++i) {
        const int m = m0 + ty * 8 + i;
        #pragma unroll
        for (int jc = 0; jc < 2; ++jc) {
            const int n = n0 + tx * 8 + jc * 4;
            f32x4 v4;
            #pragma unroll
            for (int q = 0; q < 4; ++q) {
                float v = acc[i][jc * 4 + q] + bias[n + q];
                v4[q] = v > 0.f ? v : 0.f;
            }
            *(f32x4*)(C + (size_t)m * HID + n) = v4;
        }
    }
}

__global__ void layer4f(const float* __restrict__ A, const float* __restrict__ w4,
                        const float* __restrict__ b4, float* __restrict__ Amg, int row0) {
    const int lane = threadIdx.x & 63;
    const int wave = threadIdx.x >> 6;
    const int r    = blockIdx.x * 4 + wave;
    if (row0 + r >= MPTS) return;
    const float* ap = A + (size_t)r * HID;
    float s = 0.f;
    #pragma unroll
    for (int c = 0; c < 8; ++c) {
        const int col = c * 256 + lane * 4;
        f32x4 av = *(const f32x4*)(ap + col);
        f32x4 wv = *(const f32x4*)(w4 + col);
        s += av[0] * wv[0] + av[1] * wv[1] + av[2] * wv[2] + av[3] * wv[3];
    }
    #pragma unroll
    for (int off = 32; off; off >>= 1) s += __shfl_down(s, off);
    if (lane == 0) {
        float v = s + b4[0];
        Amg[row0 + r] = v > 0.f ? v : 0.f;
    }
}

// ---------------------------------------------------------------------------
// Multigrid level: interp (2n-1) + band overwrite; all fp32 (d_out is fp32).
// ---------------------------------------------------------------------------
__global__ void mg_level(const float* __restrict__ in, float* __restrict__ outf,
                         const int* __restrict__ nbrs_base, int level,
                         const float* __restrict__ band, int n_out) {
    const int j = blockIdx.x * 256 + threadIdx.x;
    if (j >= n_out) return;
    float v;
    if (j & 1) v = 0.5f * (in[j >> 1] + in[(j >> 1) + 1]);
    else       v = in[j >> 1];
    const int stride =
        (nbrs_base[1] == 0 && nbrs_base[3] == 0 && nbrs_base[5] == 0) ? 2 : 1;
    #pragma unroll
    for (int t = 0; t < 8; ++t) {
        const int idx = nbrs_base[(level * 8 + t) * stride];
        if (j == idx) v = band[t];
    }
    outf[j] = v;
}

// ---------------------------------------------------------------------------
extern "C" void kernel_launch(void* const* d_in, const int* in_sizes, int n_in,
                              void* d_out, int out_size, void* d_ws, size_t ws_size,
                              hipStream_t stream) {
    // ---- input order detection: dict (documented) / signature / alphabetical
    int iXS=0, iNB=1, iW0=4, iB0=5, iW1=6, iB1=7, iW2=8, iB2=9,
        iW3=10, iB3=11, iW4=12, iB4=13;                       // dict default
    if (n_in >= 14) {
        if (in_sizes[0] == HID) {
            iB0=0; iB1=1; iB2=2; iB3=3; iB4=4; iNB=7;
            iW0=8; iW1=9; iW2=10; iW3=11; iW4=12; iXS=13;
        } else if (!(in_sizes[1] == 40 || in_sizes[1] == 80)) {
            iXS=0; iW0=1; iB0=2; iW1=3; iB1=4; iW2=5; iB2=6;
            iW3=7; iB3=8; iW4=9; iB4=10; iNB=11;
        }
    }
    const float* xs = (const float*)d_in[iXS];
    const int* nbrs = (const int*)d_in[iNB];
    const float* w0 = (const float*)d_in[iW0];
    const float* b0 = (const float*)d_in[iB0];
    const float* w1 = (const float*)d_in[iW1];
    const float* b1 = (const float*)d_in[iB1];
    const float* w2 = (const float*)d_in[iW2];
    const float* b2 = (const float*)d_in[iB2];
    const float* w3 = (const float*)d_in[iW3];
    const float* b3 = (const float*)d_in[iB3];
    const float* w4 = (const float*)d_in[iW4];
    const float* b4 = (const float*)d_in[iB4];

    // ---- workspace layout ----
    char* ws = (char*)d_ws;
    const size_t szAmg = 66048;
    const size_t szAh1 = 524544;
    const size_t szAh2 = 1048832;
    float* Amg = (float*)(ws);
    float* ahA = (float*)(ws + szAmg);
    float* ahB = (float*)(ws + szAmg + szAh1);
    const size_t casc_end = szAmg + szAh1 + szAh2;       // 1,639,424
    const size_t szW    = (size_t)3 * 1024 * BIMG * 2;   // 31,457,280 (fp16)
    const size_t per_tile = 2ull * 128 * HID * 4;        // 2 MB (4 fp16 act bufs)

    const int use_mfma = (ws_size >= casc_end + szW + per_tile) ? 1 : 0;

    _Float16* wp = (_Float16*)(ws + casc_end);
    const size_t buf_start = use_mfma ? (casc_end + szW) : casc_end;

    size_t avail = ws_size - buf_start;
    int CT = (int)(avail / per_tile);
    if (CT < 1) CT = 1;
    if (CT > 64) CT = 64;   // 64 mt x 8 nt2 = 512 blocks = 1 full round at 2/CU

    if (use_mfma) {
        const size_t half = (size_t)CT * 128 * HID;       // f16 elems per buffer
        _Float16* bAh = (_Float16*)(ws + buf_start);
        _Float16* bAl = bAh + half;
        _Float16* bBh = bAh + 2 * half;
        _Float16* bBl = bAh + 3 * half;

        pack_w16<<<dim3(KTIL, NTIL, 3), 256, 0, stream>>>(w1, w2, w3, wp);

        for (int t0 = 0; t0 < MTILES; t0 += CT) {
            int tiles = (MTILES - t0 < CT) ? (MTILES - t0) : CT;
            int row0 = t0 * 128;
            layer0p<<<dim3(tiles * 128), 256, 0, stream>>>(xs, w0, b0, bAh, bAl, row0);
            dim3 ggrid(tiles, 8);   // x=mt (tiles%8==0 -> same-mt blocks share XCD)
            gemm_hl<<<ggrid, 256, 0, stream>>>(bAh, bAl, wp, b1, bBh, bBl, 0, 1);
            gemm_hl<<<ggrid, 256, 0, stream>>>(bBh, bBl, wp, b2, bAh, bAl, 1, 1);
            gemm_hl<<<ggrid, 256, 0, stream>>>(bAh, bAl, wp, b3, bBh, bBl, 2, 0);
            layer4p<<<dim3(tiles), 256, 0, stream>>>(bBh, w4, b4, Amg, row0);
        }
    } else {
        float* bufA = (float*)(ws + buf_start);
        float* bufB = (float*)(ws + buf_start + (size_t)CT * 128 * HID * 4);
        for (int t0 = 0; t0 < MTILES; t0 += CT) {
            int tiles = (MTILES - t0 < CT) ? (MTILES - t0) : CT;
            int row0 = t0 * 128;
            layer0f<<<dim3(tiles * 128), 256, 0, stream>>>(xs, w0, b0, bufA, row0);
            dim3 ggrid(NTIL, tiles);
            gemm_valu<<<ggrid, 256, 0, stream>>>(bufA, w1, b1, bufB);
            gemm_valu<<<ggrid, 256, 0, stream>>>(bufB, w2, b2, bufA);
            gemm_valu<<<ggrid, 256, 0, stream>>>(bufA, w3, b3, bufB);
            layer4f<<<dim3(tiles * 32), 256, 0, stream>>>(bufB, w4, b4, Amg, row0);
        }
    }

    // multigrid cascade: 16385 -> ... -> 524289; level 4 writes d_out (fp32)
    const float* cur = Amg + 40;
    float* dsts[5] = {ahA, ahB, ahA, ahB, (float*)d_out};
    int n = 16385;
    for (int i = 0; i < 5; ++i) {
        int n_out = 2 * n - 1;
        mg_level<<<dim3((n_out + 255) / 256), 256, 0, stream>>>(
            cur, dsts[i], nbrs, i, Amg + 8 * (4 - i), n_out);
        cur = dsts[i];
        n = n_out;
    }
    (void)out_size;
}